// Round 1
// baseline (860.719 us; speedup 1.0000x reference)
//
#include <hip/hip_runtime.h>

// DifferentiableNLMS: B=32, T=2000, F=513, L=32.
// Each (b,f) is an independent length-T recurrence with 32-tap filter state.
// v1 design: one thread per (b,f) (16416 threads = 257 waves, ~1 wave/CU).
//  - W[32] and circular window xb[32] live in registers; time loop unrolled
//    x32 so all circular indices are compile-time (no scratch spills).
//  - X/Y prefetched one unroll period (32 steps) ahead directly into
//    registers via async global loads -> HBM latency fully hidden.
//  - norm maintained incrementally: norm += x_new^2 - x_old^2 (fp32 drift
//    ~1e-4 over 2000 steps, far under threshold).
//  - division via v_rcp_f32 + 1 Newton-Raphson iteration (~1 ulp).

#define LF   32      // FILTER_LENGTH
#define TT   2000
#define FF   513
#define BB   32
#define STEPSZ 0.1f
#define EPSV   1e-8f

__global__ __launch_bounds__(64, 1)
void nlms_kernel(const float* __restrict__ X, const float* __restrict__ Y,
                 const float* __restrict__ Wp, float* __restrict__ E,
                 float* __restrict__ Wout) {
    const int t = blockIdx.x * 64 + threadIdx.x;
    if (t >= BB * FF) return;
    const int b = t / FF;
    const int f = t - b * FF;

    const int colX = b * (TT * FF) + f;  // + k*FF indexes X/Y/E
    const int colW = b * (LF * FF) + f;  // + l*FF indexes W_prev/W_out

    // Filter state (registers)
    float W[LF];
#pragma unroll
    for (int l = 0; l < LF; ++l) W[l] = Wp[colW + l * FF];

    // Circular window buffer: xb[m & 31] = X[m] for m in [k-32, k-1]
    float xb[LF];
#pragma unroll
    for (int i = 0; i < LF; ++i) xb[i] = 0.0f;

    // Prefetch buffers: one full unroll period ahead
    float xn[32], yn[32];
#pragma unroll
    for (int j = 0; j < 32; ++j) {
        xn[j] = X[colX + j * FF];
        yn[j] = Y[colX + j * FF];
    }

    float norm = 0.0f;

#pragma unroll 1
    for (int kk = 0; kk < TT; kk += 32) {
#pragma unroll
        for (int j = 0; j < 32; ++j) {
            const int k = kk + j;           // uniform across wave
            const float x_new = xn[j];
            const float y     = yn[j];

            // Issue prefetch for step k+32 (clamped; duplicate loads at the
            // tail are harmless and cache-hit).
            int kpre = kk + 32 + j;
            if (kpre > TT - 1) kpre = TT - 1;
            xn[j] = X[colX + kpre * FF];
            yn[j] = Y[colX + kpre * FF];

            if (k < TT) {                   // uniform branch; false only for
                                            // the 16 dead steps of last iter
                const float x_old = xb[j];  // X[k-32] leaves the window
                norm = fmaf(x_new, x_new, norm);
                norm = fmaf(-x_old, x_old, norm);
                xb[j] = x_new;              // slot (k & 31) == j since kk%32==0

                // y_hat = sum_l W[l] * X[k-31+l]; X[k-31+l] sits in
                // xb[(j+1+l) & 31] (compile-time indices after unroll).
                float a0 = 0.f, a1 = 0.f, a2 = 0.f, a3 = 0.f;
#pragma unroll
                for (int l = 0; l < LF; l += 4) {
                    a0 = fmaf(W[l + 0], xb[(j + 1 + l + 0) & 31], a0);
                    a1 = fmaf(W[l + 1], xb[(j + 1 + l + 1) & 31], a1);
                    a2 = fmaf(W[l + 2], xb[(j + 1 + l + 2) & 31], a2);
                    a3 = fmaf(W[l + 3], xb[(j + 1 + l + 3) & 31], a3);
                }
                const float y_hat = (a0 + a1) + (a2 + a3);
                const float e = y - y_hat;
                E[colX + k * FF] = e;

                const float d = norm + EPSV;
                float r = __builtin_amdgcn_rcpf(d);
                r = r * fmaf(-d, r, 2.0f);          // 1 NR step -> ~fp32 exact
                const float c = STEPSZ * e * r;
#pragma unroll
                for (int l = 0; l < LF; ++l)
                    W[l] = fmaf(c, xb[(j + 1 + l) & 31], W[l]);
            }
        }
    }

#pragma unroll
    for (int l = 0; l < LF; ++l) Wout[colW + l * FF] = W[l];
}

extern "C" void kernel_launch(void* const* d_in, const int* in_sizes, int n_in,
                              void* d_out, int out_size, void* d_ws, size_t ws_size,
                              hipStream_t stream) {
    const float* X  = (const float*)d_in[0];   // X_hat_mag (B,T,F)
    const float* Y  = (const float*)d_in[1];   // Y_mag     (B,T,F)
    const float* Wp = (const float*)d_in[2];   // W_prev    (B,L,F)
    float* E    = (float*)d_out;                         // (B,T,F)
    float* Wout = E + (size_t)BB * TT * FF;              // (B,L,F)

    const int nthreads = BB * FF;              // 16416
    dim3 grid((nthreads + 63) / 64);
    nlms_kernel<<<grid, 64, 0, stream>>>(X, Y, Wp, E, Wout);
}

// Round 2
// 583.203 us; speedup vs baseline: 1.4758x; 1.4758x over previous
//
#include <hip/hip_runtime.h>

// DifferentiableNLMS v2: B=32, T=2000, F=513, L=32.
// P=2 lanes per (b,f) problem, 16 taps per lane.
//  - 16416 problems * 2 lanes = 513 waves (~2/CU, no SIMD straggler).
//  - Cross-lane (pair) traffic via v_mov_dpp quad_perm [1,0,3,2] (VALU pipe).
//  - Window: 16-slot circular register buffer per lane; lane1 inserts x_new,
//    lane0 inherits lane1's expiring element through the dpp swap.
//  - Prefetch 16 steps ahead = 32 outstanding loads (vmcnt max is 63; v1's
//    64-deep prefetch overflowed it and serialized on full memory latency).
//  - Incremental per-lane sum-of-squares; per-step pair-sum via dpp.

#define LF   32
#define TT   2000
#define FF   513
#define BB   32
#define STEPSZ 0.1f
#define EPSV   1e-8f
#define NP   16      // prefetch distance == window slots per lane == unroll

__device__ __forceinline__ float dpp_swap1(float v) {
    // quad_perm [1,0,3,2]: exchange with lane^1
    return __int_as_float(
        __builtin_amdgcn_mov_dpp(__float_as_int(v), 0xB1, 0xF, 0xF, true));
}

__global__ __launch_bounds__(64, 1)
void nlms_kernel(const float* __restrict__ X, const float* __restrict__ Y,
                 const float* __restrict__ Wp, float* __restrict__ E,
                 float* __restrict__ Wout) {
    const int lane = threadIdx.x;            // 0..63, all lanes live
    const int half = lane & 1;               // 0: taps 0-15, 1: taps 16-31
    const int prob = blockIdx.x * 32 + (lane >> 1);   // 513*32 = 16416 exact
    const int b = prob / FF;
    const int f = prob - b * FF;

    const float* Xc = X + (size_t)b * TT * FF + f;
    const float* Yc = Y + (size_t)b * TT * FF + f;
    float*       Ec = E + (size_t)b * TT * FF + f;
    const int colW = b * (LF * FF) + (16 * half) * FF + f;

    float W[16];
#pragma unroll
    for (int i = 0; i < 16; ++i) W[i] = Wp[colW + i * FF];

    // Circular window: slot (k & 15) gets this step's incoming element.
    // Invariant: at step k, lane h's window = X[k-31+16h .. k-16+16h],
    // zero-padded for negative indices -> init 0.
    float w[16];
#pragma unroll
    for (int i = 0; i < 16; ++i) w[i] = 0.0f;

    // Register prefetch, NP steps ahead (32 outstanding loads max).
    float xn[NP], yn[NP];
#pragma unroll
    for (int i = 0; i < NP; ++i) {
        xn[i] = Xc[i * FF];
        yn[i] = Yc[i * FF];
    }

    float s = 0.0f;   // this lane's window sum-of-squares (incremental)

#pragma unroll 1
    for (int kk = 0; kk < TT; kk += NP) {
#pragma unroll
        for (int j = 0; j < NP; ++j) {
            const int k = kk + j;
            const float x_new = xn[j];
            const float y     = yn[j];

            // Prefetch step k+NP into the slot we just freed (uniform addr
            // offset; clamp only bites in the last period, reloads are cached).
            int kp = k + NP; if (kp > TT - 1) kp = TT - 1;
            xn[j] = Xc[kp * FF];
            yn[j] = Yc[kp * FF];

            // Window slide: drop oldest, insert incoming.
            const float out = w[j];           // X[k-32+16h]
            const float sh  = dpp_swap1(out); // partner's expiring element
            const float inc = half ? x_new    // lane1 inserts X[k]
                                   : sh;      // lane0 inherits X[k-16]
            w[j] = inc;

            // Incremental sum of squares of this lane's window.
            s = fmaf(inc, inc, s);
            s = fmaf(-out, out, s);

            // Partial dot: tap i (local) reads slot (j+1+i)&15.
            float a0 = 0.f, a1 = 0.f, a2 = 0.f, a3 = 0.f;
#pragma unroll
            for (int i = 0; i < 16; i += 4) {
                a0 = fmaf(W[i + 0], w[(j + 1 + i + 0) & 15], a0);
                a1 = fmaf(W[i + 1], w[(j + 1 + i + 1) & 15], a1);
                a2 = fmaf(W[i + 2], w[(j + 1 + i + 2) & 15], a2);
                a3 = fmaf(W[i + 3], w[(j + 1 + i + 3) & 15], a3);
            }
            const float part = (a0 + a1) + (a2 + a3);

            // Pair reductions (both lanes end up with full sums).
            const float yh  = part + dpp_swap1(part);
            const float nrm = s + dpp_swap1(s);

            const float e = y - yh;
            const float d = nrm + EPSV;
            float r = __builtin_amdgcn_rcpf(d);
            r = r * fmaf(-d, r, 2.0f);        // 1 NR step
            const float c = (STEPSZ * e) * r;

#pragma unroll
            for (int i = 0; i < 16; ++i)
                W[i] = fmaf(c, w[(j + 1 + i) & 15], W[i]);

            if (half == 0) Ec[k * FF] = e;    // e identical in both lanes
        }
    }

#pragma unroll
    for (int i = 0; i < 16; ++i) Wout[colW + i * FF] = W[i];
}

extern "C" void kernel_launch(void* const* d_in, const int* in_sizes, int n_in,
                              void* d_out, int out_size, void* d_ws, size_t ws_size,
                              hipStream_t stream) {
    const float* X  = (const float*)d_in[0];   // X_hat_mag (B,T,F)
    const float* Y  = (const float*)d_in[1];   // Y_mag     (B,T,F)
    const float* Wp = (const float*)d_in[2];   // W_prev    (B,L,F)
    float* E    = (float*)d_out;               // (B,T,F)
    float* Wout = E + (size_t)BB * TT * FF;    // (B,L,F)

    // 513 blocks x 64 threads: 513 waves, 32 problems each, zero remainder.
    nlms_kernel<<<dim3(513), dim3(64), 0, stream>>>(X, Y, Wp, E, Wout);
}